// Round 7
// baseline (46.281 us; speedup 1.0000x reference)
//
#include <hip/hip_runtime.h>
#include <math.h>

#define BB 2048   // batch B
#define NN 512    // classes N
#define DD 256    // dim D
#define GRID 256  // exactly 1 block per CU

typedef __attribute__((ext_vector_type(8))) short s16x8;   // 8 bf16
typedef __attribute__((ext_vector_type(4))) float f32x4;

#define MFMA_BF16 __builtin_amdgcn_mfma_f32_16x16x32_bf16

__device__ __forceinline__ ushort f2bf(float f) {          // RNE f32->bf16
    union { float f; unsigned u; } c; c.f = f;
    return (ushort)((c.u + 0x7fffu + ((c.u >> 16) & 1u)) >> 16);
}
__device__ __forceinline__ float bf2f(ushort h) {
    union { unsigned u; float f; } c; c.u = ((unsigned)h) << 16;
    return c.f;
}

// scale 4 floats, split each into bf16 hi + bf16 lo (RNE both), pack pairs
__device__ __forceinline__ void split4(f32x4 v, float s, uint2* hi, uint2* lo) {
    float a = v.x * s, b = v.y * s, c = v.z * s, d = v.w * s;
    ushort ha = f2bf(a), hb = f2bf(b), hc = f2bf(c), hd = f2bf(d);
    ushort la = f2bf(a - bf2f(ha)), lb = f2bf(b - bf2f(hb));
    ushort lc = f2bf(c - bf2f(hc)), ld = f2bf(d - bf2f(hd));
    hi->x = (unsigned)ha | ((unsigned)hb << 16);
    hi->y = (unsigned)hc | ((unsigned)hd << 16);
    lo->x = (unsigned)la | ((unsigned)lb << 16);
    lo->y = (unsigned)lc | ((unsigned)ld << 16);
}

// Single kernel, 256 blocks x 512 threads (8 waves), software grid barrier.
// Phase 1: wave g = bid*8+w transforms X row g (and P/A row g if g < NN).
// Barrier: syncthreads (drain block stores) -> t0 release-fence + add ->
//          t0 spin -> t0 acquire-fence -> syncthreads.
// Phase 2: 64x64 tile per block; whole-K X in 64 KiB LDS; B frags in VGPRs;
//          8 x {4 ds_read_b128 + 12 MFMA}; fused asinh epilogue.
__global__ __launch_bounds__(512, 2) void hmlr_one(
    const float* __restrict__ x, const float* __restrict__ a_vals,
    const float* __restrict__ p_vals,
    ushort* __restrict__ Xh, ushort* __restrict__ Xl,
    ushort* __restrict__ Ph, ushort* __restrict__ Pl,
    ushort* __restrict__ Ah, ushort* __restrict__ Al,
    float* __restrict__ y2, float* __restrict__ p2s, float* __restrict__ pas,
    float* __restrict__ ans, float* __restrict__ ks,
    unsigned* __restrict__ flag, float* __restrict__ out)
{
    extern __shared__ ushort T[];          // [2][64][256] ushort = 64 KiB

    const int t    = threadIdx.x;
    const int lane = t & 63;
    const int w    = t >> 6;               // wave 0..7
    const int bid  = blockIdx.x;

    // ------------------------- phase 1: transforms -------------------------
    {
        const int e0 = lane * 4;
        const int r  = bid * 8 + w;        // X row 0..2047
        f32x4 v = *(const f32x4*)&x[(size_t)r * DD + e0];
        float ss = v.x * v.x + v.y * v.y + v.z * v.z + v.w * v.w;
        #pragma unroll
        for (int m = 32; m; m >>= 1) ss += __shfl_xor(ss, m, 64);
        float norm0 = sqrtf(ss);
        float fac = fminf(1.0f, 1.0f / (norm0 + 1e-5f));    // CLIP_R = 1
        float u = fmaxf(norm0 * fac, 1e-5f);
        float th = tanhf(u);                                 // sqrt_c = 1
        float en = fmaxf(th, 1e-5f);
        float wgt = (en > 0.999f) ? (0.999f / en) : 1.0f;    // project
        float s = fac * (th / u) * wgt;                      // x -> xb scale
        if (lane == 0) { float fn = th * wgt; y2[r] = fn * fn; }
        uint2 hi, lo;
        split4(v, s, &hi, &lo);
        int es = e0 ^ ((r & 7) << 3);                        // pre-swizzle
        *(uint2*)&Xh[(size_t)r * DD + es] = hi;
        *(uint2*)&Xl[(size_t)r * DD + es] = lo;

        if (r < NN) {                                        // also P/A row r
            const int n = r;
            f32x4 pv = *(const f32x4*)&p_vals[(size_t)n * DD + e0];
            f32x4 av = *(const f32x4*)&a_vals[(size_t)n * DD + e0];
            float sp = pv.x * pv.x + pv.y * pv.y + pv.z * pv.z + pv.w * pv.w;
            float sa = av.x * av.x + av.y * av.y + av.z * av.z + av.w * av.w;
            float sx = pv.x * av.x + pv.y * av.y + pv.z * av.z + pv.w * av.w;
            #pragma unroll
            for (int m = 32; m; m >>= 1) {
                sp += __shfl_xor(sp, m, 64);
                sa += __shfl_xor(sa, m, 64);
                sx += __shfl_xor(sx, m, 64);
            }
            float up = fmaxf(sqrtf(sp), 1e-5f);
            float thp = tanhf(up);
            float spp = thp / up;                            // p -> p_poincare
            float p2 = thp * thp;
            float conf = 1.0f - p2;                          // conformal
            if (lane == 0) {
                p2s[n] = p2;
                pas[n] = spp * conf * sx;                    // P . A
                float an = sqrtf(sa) * conf;                 // ||a_poincare||
                ans[n] = an;
                ks[n] = (2.0f / conf) * an;                  // lam * a_norm
            }
            uint2 h2, l2;
            split4(pv, spp, &h2, &l2);                       // PLAIN layout
            *(uint2*)&Ph[(size_t)n * DD + e0] = h2;
            *(uint2*)&Pl[(size_t)n * DD + e0] = l2;
            split4(av, conf, &h2, &l2);
            *(uint2*)&Ah[(size_t)n * DD + e0] = h2;
            *(uint2*)&Al[(size_t)n * DD + e0] = l2;
        }
    }

    // ------------------------- grid barrier -------------------------
    __syncthreads();   // ALL block stores drained (vmcnt(0) before s_barrier)
    if (t == 0) {
        __builtin_amdgcn_fence(__ATOMIC_RELEASE, "agent");   // L2 writeback
        __hip_atomic_fetch_add(flag, 1u, __ATOMIC_RELAXED, __HIP_MEMORY_SCOPE_AGENT);
        int spins = 0;
        while (__hip_atomic_load(flag, __ATOMIC_RELAXED, __HIP_MEMORY_SCOPE_AGENT)
                   < (unsigned)GRID && ++spins < (1 << 26)) {
            __builtin_amdgcn_s_sleep(2);
        }
        __builtin_amdgcn_fence(__ATOMIC_ACQUIRE, "agent");   // L1/L2 invalidate
    }
    __syncthreads();

    // ------------------- phase 2: GEMM + epilogue -------------------
    const int n0  = (bid & 7) * 64;
    const int b0  = (bid >> 3) * 64;
    const int wr  = w >> 2;                // b half (32 rows)
    const int wc  = w & 3;                 // n strip (16 cols)
    const int gb8 = (lane >> 4) * 8;       // elem offset of this lane's 16B group
    const int ram = wr * 32 + (lane & 15);
    const int rbn = wc * 16 + (lane & 15);

    // stage whole-K X hi/lo into LDS (wave w: rows w*8 .. w*8+7 of both mats)
    {
        const ushort* gh = Xh + (size_t)(b0 + w * 8) * DD + (lane >> 5) * DD + (lane & 31) * 8;
        const ushort* gl = Xl + (size_t)(b0 + w * 8) * DD + (lane >> 5) * DD + (lane & 31) * 8;
        ushort* lh = T + (size_t)(w * 8) * DD;
        ushort* ll = T + (size_t)64 * DD + (size_t)(w * 8) * DD;
        #pragma unroll
        for (int j = 0; j < 4; ++j) {      // each instr: 2 rows (1 KiB)
            __builtin_amdgcn_global_load_lds(
                (const __attribute__((address_space(1))) unsigned int*)(const void*)(gh + j * 2 * DD),
                (__attribute__((address_space(3))) unsigned int*)(void*)(lh + j * 2 * DD),
                16, 0, 0);
            __builtin_amdgcn_global_load_lds(
                (const __attribute__((address_space(1))) unsigned int*)(const void*)(gl + j * 2 * DD),
                (__attribute__((address_space(3))) unsigned int*)(void*)(ll + j * 2 * DD),
                16, 0, 0);
        }
    }

    // preload B fragments (plain layout) into registers: 32 x 16B
    const ushort* prh = Ph + (size_t)(n0 + rbn) * DD;
    const ushort* prl = Pl + (size_t)(n0 + rbn) * DD;
    const ushort* arh = Ah + (size_t)(n0 + rbn) * DD;
    const ushort* arl = Al + (size_t)(n0 + rbn) * DD;
    s16x8 phf[8], plf[8], ahf[8], alf[8];
    #pragma unroll
    for (int q = 0; q < 8; ++q) {
        int e = q * 32 + gb8;
        phf[q] = *(const s16x8*)(prh + e);
        plf[q] = *(const s16x8*)(prl + e);
        ahf[q] = *(const s16x8*)(arh + e);
        alf[q] = *(const s16x8*)(arl + e);
    }

    __syncthreads();                       // X tiles resident (drains vmcnt)

    f32x4 axy0 = {0.f,0.f,0.f,0.f}, axy1 = {0.f,0.f,0.f,0.f};
    f32x4 axa0 = {0.f,0.f,0.f,0.f}, axa1 = {0.f,0.f,0.f,0.f};
    const int swzA = (ram & 7) << 3;       // same for ram+16
    const ushort* r0h = T + (size_t)ram * DD;
    const ushort* r1h = T + (size_t)(ram + 16) * DD;
    const ushort* r0l = T + (size_t)64 * DD + (size_t)ram * DD;
    const ushort* r1l = T + (size_t)64 * DD + (size_t)(ram + 16) * DD;

    #pragma unroll
    for (int q = 0; q < 8; ++q) {
        int f = q * 32 + gb8;
        int p = (f & ~63) | ((f & 63) ^ swzA);
        s16x8 xh0 = *(const s16x8*)(r0h + p);
        s16x8 xh1 = *(const s16x8*)(r1h + p);
        s16x8 xl0 = *(const s16x8*)(r0l + p);
        s16x8 xl1 = *(const s16x8*)(r1l + p);
        axy0 = MFMA_BF16(xh0, phf[q], axy0, 0, 0, 0);
        axy0 = MFMA_BF16(xh0, plf[q], axy0, 0, 0, 0);
        axy0 = MFMA_BF16(xl0, phf[q], axy0, 0, 0, 0);
        axy1 = MFMA_BF16(xh1, phf[q], axy1, 0, 0, 0);
        axy1 = MFMA_BF16(xh1, plf[q], axy1, 0, 0, 0);
        axy1 = MFMA_BF16(xl1, phf[q], axy1, 0, 0, 0);
        axa0 = MFMA_BF16(xh0, ahf[q], axa0, 0, 0, 0);
        axa0 = MFMA_BF16(xh0, alf[q], axa0, 0, 0, 0);
        axa0 = MFMA_BF16(xl0, ahf[q], axa0, 0, 0, 0);
        axa1 = MFMA_BF16(xh1, ahf[q], axa1, 0, 0, 0);
        axa1 = MFMA_BF16(xh1, alf[q], axa1, 0, 0, 0);
        axa1 = MFMA_BF16(xl1, ahf[q], axa1, 0, 0, 0);
    }

    // epilogue: C/D map col=lane&15, row=(lane>>4)*4+reg
    const int n = n0 + rbn;
    const float p2 = p2s[n], pa = pas[n], an = ans[n], kk = ks[n];
    #pragma unroll
    for (int m = 0; m < 2; ++m) {
        f32x4 acc_xy = m ? axy1 : axy0;
        f32x4 acc_xa = m ? axa1 : axa0;
        #pragma unroll
        for (int rg = 0; rg < 4; ++rg) {
            int b = b0 + wr * 32 + m * 16 + (lane >> 4) * 4 + rg;
            float yy  = y2[b];
            float xy  = -acc_xy[rg];                     // (-P).X
            float xa  =  acc_xa[rg];
            float dnm = 1.f + 2.f * xy + p2 * yy + 1e-5f;
            float alpha = (1.f + 2.f * xy + yy) / dnm;   // coeff on (-P)
            float beta  = (1.f - p2) / dnm;              // coeff on X
            float num  = 2.f * (beta * xa - alpha * pa);
            float mob2 = alpha * alpha * p2 + beta * beta * yy
                       + 2.f * alpha * beta * xy;
            float den  = an * (1.f - mob2);
            out[(size_t)b * NN + n] = kk * asinhf(num / den);
        }
    }
}

extern "C" void kernel_launch(void* const* d_in, const int* in_sizes, int n_in,
                              void* d_out, int out_size, void* d_ws, size_t ws_size,
                              hipStream_t stream) {
    const float* x      = (const float*)d_in[0];
    const float* a_vals = (const float*)d_in[1];
    const float* p_vals = (const float*)d_in[2];
    float* out = (float*)d_out;

    ushort* Xh = (ushort*)d_ws;                 // [BB][DD] bf16 hi (pre-swizzled)
    ushort* Xl = Xh + (size_t)BB * DD;
    ushort* Ph = Xl + (size_t)BB * DD;          // [NN][DD] plain
    ushort* Pl = Ph + (size_t)NN * DD;
    ushort* Ah = Pl + (size_t)NN * DD;
    ushort* Al = Ah + (size_t)NN * DD;
    float*  y2  = (float*)(Al + (size_t)NN * DD);
    float*  p2s = y2 + BB;
    float*  pas = p2s + NN;
    float*  ans = pas + NN;
    float*  ks  = ans + NN;
    unsigned* flag = (unsigned*)((char*)d_ws + (4u << 20));   // @4 MiB, clear of arrays

    (void)hipFuncSetAttribute(reinterpret_cast<const void*>(hmlr_one),
                              hipFuncAttributeMaxDynamicSharedMemorySize, 65536);

    hipMemsetAsync(flag, 0, sizeof(unsigned), stream);        // reset barrier each call
    hipLaunchKernelGGL(hmlr_one, dim3(GRID), dim3(512), 65536, stream,
                       x, a_vals, p_vals, Xh, Xl, Ph, Pl, Ah, Al,
                       y2, p2s, pas, ans, ks, flag, out);
}

// Round 8
// 27.843 us; speedup vs baseline: 1.6622x; 1.6622x over previous
//
#include <hip/hip_runtime.h>
#include <math.h>

#define BB 2048   // batch B
#define NN 512    // classes N
#define DD 256    // dim D

typedef __attribute__((ext_vector_type(8))) short s16x8;   // 8 bf16
typedef __attribute__((ext_vector_type(4))) float f32x4;

#define MFMA_BF16 __builtin_amdgcn_mfma_f32_16x16x32_bf16

__device__ __forceinline__ ushort f2bf(float f) {          // RNE f32->bf16
    union { float f; unsigned u; } c; c.f = f;
    return (ushort)((c.u + 0x7fffu + ((c.u >> 16) & 1u)) >> 16);
}
__device__ __forceinline__ float bf2f(ushort h) {
    union { unsigned u; float f; } c; c.u = ((unsigned)h) << 16;
    return c.f;
}

// scale 4 floats, split each into bf16 hi + bf16 lo (RNE both), pack pairs
__device__ __forceinline__ void split4(f32x4 v, float s, uint2* hi, uint2* lo) {
    float a = v.x * s, b = v.y * s, c = v.z * s, d = v.w * s;
    ushort ha = f2bf(a), hb = f2bf(b), hc = f2bf(c), hd = f2bf(d);
    ushort la = f2bf(a - bf2f(ha)), lb = f2bf(b - bf2f(hb));
    ushort lc = f2bf(c - bf2f(hc)), ld = f2bf(d - bf2f(hd));
    hi->x = (unsigned)ha | ((unsigned)hb << 16);
    hi->y = (unsigned)hc | ((unsigned)hd << 16);
    lo->x = (unsigned)la | ((unsigned)lb << 16);
    lo->y = (unsigned)lc | ((unsigned)ld << 16);
}

// ---------------- K1: one WAVE per row, no barriers ----------------
// Waves [0,BB): x -> Poincare ball, bf16 hi/lo PRE-SWIZZLED
//   (el ^= (row&7)<<3 within each 64-elem chunk).
// Waves [BB,BB+NN): p,a -> p_poincare / a_poincare (PLAIN layout) + scalars.
__global__ __launch_bounds__(512) void hmlr_transform(
    const float* __restrict__ x, const float* __restrict__ a_vals,
    const float* __restrict__ p_vals,
    ushort* __restrict__ Xh, ushort* __restrict__ Xl,
    ushort* __restrict__ Ph, ushort* __restrict__ Pl,
    ushort* __restrict__ Ah, ushort* __restrict__ Al,
    float* __restrict__ y2, float* __restrict__ p2s, float* __restrict__ pas,
    float* __restrict__ ans, float* __restrict__ ks)
{
    const int lane = threadIdx.x & 63;
    const int wid  = blockIdx.x * 8 + (threadIdx.x >> 6);   // 0..BB+NN-1
    const int e0   = lane * 4;

    if (wid < BB) {
        const int r = wid;
        f32x4 v = *(const f32x4*)&x[(size_t)r * DD + e0];
        float ss = v.x * v.x + v.y * v.y + v.z * v.z + v.w * v.w;
        #pragma unroll
        for (int m = 32; m; m >>= 1) ss += __shfl_xor(ss, m, 64);
        float norm0 = sqrtf(ss);
        float fac = fminf(1.0f, 1.0f / (norm0 + 1e-5f));    // CLIP_R = 1
        float u = fmaxf(norm0 * fac, 1e-5f);
        float th = tanhf(u);                                 // sqrt_c = 1
        float en = fmaxf(th, 1e-5f);
        float wgt = (en > 0.999f) ? (0.999f / en) : 1.0f;    // project
        float s = fac * (th / u) * wgt;                      // x -> xb scale
        if (lane == 0) { float fn = th * wgt; y2[r] = fn * fn; }
        uint2 hi, lo;
        split4(v, s, &hi, &lo);
        int es = e0 ^ ((r & 7) << 3);                        // pre-swizzle
        *(uint2*)&Xh[(size_t)r * DD + es] = hi;
        *(uint2*)&Xl[(size_t)r * DD + es] = lo;
    } else {
        const int n = wid - BB;
        f32x4 pv = *(const f32x4*)&p_vals[(size_t)n * DD + e0];
        f32x4 av = *(const f32x4*)&a_vals[(size_t)n * DD + e0];
        float sp = pv.x * pv.x + pv.y * pv.y + pv.z * pv.z + pv.w * pv.w;
        float sa = av.x * av.x + av.y * av.y + av.z * av.z + av.w * av.w;
        float sx = pv.x * av.x + pv.y * av.y + pv.z * av.z + pv.w * av.w;
        #pragma unroll
        for (int m = 32; m; m >>= 1) {
            sp += __shfl_xor(sp, m, 64);
            sa += __shfl_xor(sa, m, 64);
            sx += __shfl_xor(sx, m, 64);
        }
        float u = fmaxf(sqrtf(sp), 1e-5f);
        float th = tanhf(u);
        float spp = th / u;                                  // p -> p_poincare
        float p2 = th * th;
        float conf = 1.0f - p2;                              // conformal
        if (lane == 0) {
            p2s[n] = p2;
            pas[n] = spp * conf * sx;                        // P . A
            float an = sqrtf(sa) * conf;                     // ||a_poincare||
            ans[n] = an;
            ks[n] = (2.0f / conf) * an;                      // lam * a_norm
        }
        uint2 h2, l2;
        split4(pv, spp, &h2, &l2);                           // PLAIN layout
        *(uint2*)&Ph[(size_t)n * DD + e0] = h2;
        *(uint2*)&Pl[(size_t)n * DD + e0] = l2;
        split4(av, conf, &h2, &l2);
        *(uint2*)&Ah[(size_t)n * DD + e0] = h2;
        *(uint2*)&Al[(size_t)n * DD + e0] = l2;
    }
}

// ---------------- K2: 64x64 tile, 8 waves, whole-K X in LDS ----------------
// One global_load_lds stage (64 KiB, one drain); B frags pinned in VGPRs;
// 8 x {4 swizzled ds_read_b128 + 12 MFMA}; fused asinh epilogue.
__global__ __launch_bounds__(512, 1) void hmlr_gemm(
    const ushort* __restrict__ Xh, const ushort* __restrict__ Xl,
    const ushort* __restrict__ Ph, const ushort* __restrict__ Pl,
    const ushort* __restrict__ Ah, const ushort* __restrict__ Al,
    const float* __restrict__ y2, const float* __restrict__ p2s,
    const float* __restrict__ pas, const float* __restrict__ ans,
    const float* __restrict__ ks, float* __restrict__ out)
{
    extern __shared__ ushort T[];          // [2][64][256] ushort = 64 KiB

    const int t    = threadIdx.x;
    const int lane = t & 63;
    const int w    = t >> 6;               // wave 0..7
    const int bid  = blockIdx.x;
    const int n0   = (bid & 7) * 64;
    const int b0   = (bid >> 3) * 64;
    const int wr   = w >> 2;               // b half (32 rows)
    const int wc   = w & 3;                // n strip (16 cols)
    const int gb8  = (lane >> 4) * 8;      // this lane's 16B group (elems)
    const int ram  = wr * 32 + (lane & 15);
    const int rbn  = wc * 16 + (lane & 15);

    // stage whole-K X hi/lo into LDS (wave w: rows w*8 .. w*8+7 of both mats)
    {
        const ushort* gh = Xh + (size_t)(b0 + w * 8) * DD + (lane >> 5) * DD + (lane & 31) * 8;
        const ushort* gl = Xl + (size_t)(b0 + w * 8) * DD + (lane >> 5) * DD + (lane & 31) * 8;
        ushort* lh = T + (size_t)(w * 8) * DD;
        ushort* ll = T + (size_t)64 * DD + (size_t)(w * 8) * DD;
        #pragma unroll
        for (int j = 0; j < 4; ++j) {      // each instr: 2 rows (1 KiB/wave)
            __builtin_amdgcn_global_load_lds(
                (const __attribute__((address_space(1))) unsigned int*)(const void*)(gh + j * 2 * DD),
                (__attribute__((address_space(3))) unsigned int*)(void*)(lh + j * 2 * DD),
                16, 0, 0);
            __builtin_amdgcn_global_load_lds(
                (const __attribute__((address_space(1))) unsigned int*)(const void*)(gl + j * 2 * DD),
                (__attribute__((address_space(3))) unsigned int*)(void*)(ll + j * 2 * DD),
                16, 0, 0);
        }
    }

    // preload B fragments (plain layout) into registers and PIN them
    const ushort* prh = Ph + (size_t)(n0 + rbn) * DD;
    const ushort* prl = Pl + (size_t)(n0 + rbn) * DD;
    const ushort* arh = Ah + (size_t)(n0 + rbn) * DD;
    const ushort* arl = Al + (size_t)(n0 + rbn) * DD;
    s16x8 phf[8], plf[8], ahf[8], alf[8];
    #pragma unroll
    for (int q = 0; q < 8; ++q) {
        int e = q * 32 + gb8;
        phf[q] = *(const s16x8*)(prh + e);
        plf[q] = *(const s16x8*)(prl + e);
        ahf[q] = *(const s16x8*)(arh + e);
        alf[q] = *(const s16x8*)(arl + e);
    }
    #pragma unroll
    for (int q = 0; q < 8; ++q) {          // keep-alive: forbid re-load sinking
        asm volatile("" :: "v"(phf[q]), "v"(plf[q]), "v"(ahf[q]), "v"(alf[q]));
    }

    __syncthreads();                       // X tiles resident (drains vmcnt)

    f32x4 axy0 = {0.f,0.f,0.f,0.f}, axy1 = {0.f,0.f,0.f,0.f};
    f32x4 axa0 = {0.f,0.f,0.f,0.f}, axa1 = {0.f,0.f,0.f,0.f};
    const int swzA = (ram & 7) << 3;       // same for ram+16
    const ushort* r0h = T + (size_t)ram * DD;
    const ushort* r1h = T + (size_t)(ram + 16) * DD;
    const ushort* r0l = T + (size_t)64 * DD + (size_t)ram * DD;
    const ushort* r1l = T + (size_t)64 * DD + (size_t)(ram + 16) * DD;

    #pragma unroll
    for (int q = 0; q < 8; ++q) {
        int f = q * 32 + gb8;
        int p = (f & ~63) | ((f & 63) ^ swzA);
        s16x8 xh0 = *(const s16x8*)(r0h + p);
        s16x8 xh1 = *(const s16x8*)(r1h + p);
        s16x8 xl0 = *(const s16x8*)(r0l + p);
        s16x8 xl1 = *(const s16x8*)(r1l + p);
        axy0 = MFMA_BF16(xh0, phf[q], axy0, 0, 0, 0);
        axy0 = MFMA_BF16(xh0, plf[q], axy0, 0, 0, 0);
        axy0 = MFMA_BF16(xl0, phf[q], axy0, 0, 0, 0);
        axy1 = MFMA_BF16(xh1, phf[q], axy1, 0, 0, 0);
        axy1 = MFMA_BF16(xh1, plf[q], axy1, 0, 0, 0);
        axy1 = MFMA_BF16(xl1, phf[q], axy1, 0, 0, 0);
        axa0 = MFMA_BF16(xh0, ahf[q], axa0, 0, 0, 0);
        axa0 = MFMA_BF16(xh0, alf[q], axa0, 0, 0, 0);
        axa0 = MFMA_BF16(xl0, ahf[q], axa0, 0, 0, 0);
        axa1 = MFMA_BF16(xh1, ahf[q], axa1, 0, 0, 0);
        axa1 = MFMA_BF16(xh1, alf[q], axa1, 0, 0, 0);
        axa1 = MFMA_BF16(xl1, ahf[q], axa1, 0, 0, 0);
    }

    // epilogue: C/D map col=lane&15, row=(lane>>4)*4+reg
    const int n = n0 + rbn;
    const float p2 = p2s[n], pa = pas[n], an = ans[n], kk = ks[n];
    #pragma unroll
    for (int m = 0; m < 2; ++m) {
        f32x4 acc_xy = m ? axy1 : axy0;
        f32x4 acc_xa = m ? axa1 : axa0;
        #pragma unroll
        for (int rg = 0; rg < 4; ++rg) {
            int b = b0 + wr * 32 + m * 16 + (lane >> 4) * 4 + rg;
            float yy  = y2[b];
            float xy  = -acc_xy[rg];                     // (-P).X
            float xa  =  acc_xa[rg];
            float dnm = 1.f + 2.f * xy + p2 * yy + 1e-5f;
            float alpha = (1.f + 2.f * xy + yy) / dnm;   // coeff on (-P)
            float beta  = (1.f - p2) / dnm;              // coeff on X
            float num  = 2.f * (beta * xa - alpha * pa);
            float mob2 = alpha * alpha * p2 + beta * beta * yy
                       + 2.f * alpha * beta * xy;
            float den  = an * (1.f - mob2);
            out[(size_t)b * NN + n] = kk * asinhf(num / den);
        }
    }
}

extern "C" void kernel_launch(void* const* d_in, const int* in_sizes, int n_in,
                              void* d_out, int out_size, void* d_ws, size_t ws_size,
                              hipStream_t stream) {
    const float* x      = (const float*)d_in[0];
    const float* a_vals = (const float*)d_in[1];
    const float* p_vals = (const float*)d_in[2];
    float* out = (float*)d_out;

    ushort* Xh = (ushort*)d_ws;                 // [BB][DD] bf16 hi (pre-swizzled)
    ushort* Xl = Xh + (size_t)BB * DD;
    ushort* Ph = Xl + (size_t)BB * DD;          // [NN][DD] plain
    ushort* Pl = Ph + (size_t)NN * DD;
    ushort* Ah = Pl + (size_t)NN * DD;
    ushort* Al = Ah + (size_t)NN * DD;
    float*  y2  = (float*)(Al + (size_t)NN * DD);
    float*  p2s = y2 + BB;
    float*  pas = p2s + NN;
    float*  ans = pas + NN;
    float*  ks  = ans + NN;

    (void)hipFuncSetAttribute(reinterpret_cast<const void*>(hmlr_gemm),
                              hipFuncAttributeMaxDynamicSharedMemorySize, 65536);

    hipLaunchKernelGGL(hmlr_transform, dim3((BB + NN) / 8), dim3(512), 0, stream,
                       x, a_vals, p_vals, Xh, Xl, Ph, Pl, Ah, Al,
                       y2, p2s, pas, ans, ks);
    hipLaunchKernelGGL(hmlr_gemm, dim3(NN / 64 * (BB / 64)), dim3(512), 65536, stream,
                       Xh, Xl, Ph, Pl, Ah, Al, y2, p2s, pas, ans, ks, out);
}